// Round 1
// baseline (3517.642 us; speedup 1.0000x reference)
//
#include <hip/hip_runtime.h>

#define LSEQ 384
#define DIM 128
#define NHEADS 4
#define HDIM 16

// ---------- helpers ----------
__device__ __forceinline__ float bf2f_lo(unsigned int u) { return __uint_as_float(u << 16); }
__device__ __forceinline__ float bf2f_hi(unsigned int u) { return __uint_as_float(u & 0xFFFF0000u); }
__device__ __forceinline__ unsigned short f2bf(float f) {
    unsigned int u = __float_as_uint(f);
    u += 0x7FFFu + ((u >> 16) & 1u);   // round-to-nearest-even
    return (unsigned short)(u >> 16);
}
__device__ __forceinline__ float wred_sum(float v) {
#pragma unroll
    for (int off = 32; off > 0; off >>= 1) v += __shfl_xor(v, off, 64);
    return v;
}
__device__ __forceinline__ float wred_max(float v) {
#pragma unroll
    for (int off = 32; off > 0; off >>= 1) v = fmaxf(v, __shfl_xor(v, off, 64));
    return v;
}
__device__ __forceinline__ float ldval(const float* p) { return *p; }
__device__ __forceinline__ float ldval(const unsigned short* p) { return __uint_as_float(((unsigned int)*p) << 16); }
__device__ __forceinline__ void stval(float* p, float v) { *p = v; }
__device__ __forceinline__ void stval(unsigned short* p, float v) { *p = f2bf(v); }

// ---------- fused gated axial attention (one (line, head) per block) ----------
// x is read as x[b*sb + n*sn + d]; attn_out[b][n][h*16+d] contiguous.
__global__ __launch_bounds__(256, 2) void attn_kernel(
    const float* __restrict__ x, long sb, long sn,
    const float* __restrict__ ln_g, const float* __restrict__ ln_b,
    const float* __restrict__ w_qkv,   // (192,128)
    const float* __restrict__ w_gate,  // (64,128)
    const float* __restrict__ b_gate,  // (64)
    float* __restrict__ attn_out)      // (384,384,64)
{
    const int b    = blockIdx.x;
    const int h    = blockIdx.y;
    const int tid  = threadIdx.x;
    const int wave = tid >> 6;
    const int lane = tid & 63;

    // bf16 pairs; per-token row = 9 dwords (8 used + 1 pad -> stride 9, conflict-free)
    __shared__ unsigned int qkvg[4 * LSEQ * 9];
    __shared__ __align__(16) float xn[4][DIM];
    __shared__ __align__(16) float xr[4][DIM];
    __shared__ float ms[LSEQ];
    __shared__ float linv[LSEQ];

    const int which = lane >> 4;   // 0=q 1=k 2=v 3=gate
    const int sub   = lane & 15;

    const float* wrow;
    if (which < 3) wrow = w_qkv + (long)(which * 64 + h * HDIM + sub) * DIM;
    else           wrow = w_gate + (long)(h * HDIM + sub) * DIM;

    float4 wreg[32];
#pragma unroll
    for (int p = 0; p < 32; ++p) wreg[p] = ((const float4*)wrow)[p];

    const float gb   = b_gate[h * HDIM + sub];
    const float lng0 = ln_g[lane], lng1 = ln_g[lane + 64];
    const float lnb0 = ln_b[lane], lnb1 = ln_b[lane + 64];

    // ---- phase 1: LN + qkv/gate projection, stage bf16 into LDS ----
    for (int n = wave; n < LSEQ; n += 4) {
        const float* xp = x + (long)b * sb + (long)n * sn;
        float x0 = xp[lane], x1 = xp[lane + 64];
        float s  = wred_sum(x0 + x1);
        float sq = wred_sum(x0 * x0 + x1 * x1);
        float mean = s * (1.f / 128.f);
        float var  = sq * (1.f / 128.f) - mean * mean;
        float inv  = rsqrtf(var + 1e-5f);
        xn[wave][lane]      = (x0 - mean) * inv * lng0 + lnb0;
        xn[wave][lane + 64] = (x1 - mean) * inv * lng1 + lnb1;
        xr[wave][lane]      = x0;
        xr[wave][lane + 64] = x1;
        __syncthreads();
        const float* src = (which == 3) ? xr[wave] : xn[wave];
        float acc = 0.f;
#pragma unroll
        for (int p = 0; p < 32; ++p) {
            float4 xv = ((const float4*)src)[p];
            acc = fmaf(xv.x, wreg[p].x, acc);
            acc = fmaf(xv.y, wreg[p].y, acc);
            acc = fmaf(xv.z, wreg[p].z, acc);
            acc = fmaf(xv.w, wreg[p].w, acc);
        }
        if (which == 3) acc = 1.f / (1.f + __expf(-(acc + gb)));
        ((unsigned short*)qkvg)[(which * LSEQ + n) * 18 + sub] = f2bf(acc);
        __syncthreads();
    }

    // ---- phase 2: per-row softmax stats (softmax over j for each row i) ----
    for (int i = wave; i < LSEQ; i += 4) {
        const unsigned int* qrow = qkvg + i * 9;
        float qf[16];
#pragma unroll
        for (int p = 0; p < 8; ++p) {
            unsigned int u = qrow[p];
            qf[2 * p] = bf2f_lo(u); qf[2 * p + 1] = bf2f_hi(u);
        }
        float sv[6];
        float m = -1e30f;
#pragma unroll
        for (int jj = 0; jj < 6; ++jj) {
            int j = lane + jj * 64;
            const unsigned int* krow = qkvg + (LSEQ + j) * 9;
            float acc = 0.f;
#pragma unroll
            for (int p = 0; p < 8; ++p) {
                unsigned int u = krow[p];
                acc = fmaf(qf[2 * p],     bf2f_lo(u), acc);
                acc = fmaf(qf[2 * p + 1], bf2f_hi(u), acc);
            }
            sv[jj] = 0.25f * acc;
            m = fmaxf(m, sv[jj]);
        }
        m = wred_max(m);
        float l = 0.f;
#pragma unroll
        for (int jj = 0; jj < 6; ++jj) l += __expf(sv[jj] - m);
        l = wred_sum(l);
        if (lane == 0) { ms[i] = m; linv[i] = 1.f / l; }
    }
    __syncthreads();

    // ---- phase 3: out[j,d] = sum_i exp(s_ij - m_i)/l_i * v[i,d], then gate ----
    for (int j = tid; j < LSEQ; j += 256) {
        const unsigned int* krow = qkvg + (LSEQ + j) * 9;
        float kf[16];
#pragma unroll
        for (int p = 0; p < 8; ++p) {
            unsigned int u = krow[p];
            kf[2 * p] = bf2f_lo(u); kf[2 * p + 1] = bf2f_hi(u);
        }
        float o[16];
#pragma unroll
        for (int d = 0; d < 16; ++d) o[d] = 0.f;

        for (int i = 0; i < LSEQ; ++i) {
            const unsigned int* qrow = qkvg + i * 9;
            float acc = 0.f;
#pragma unroll
            for (int p = 0; p < 8; ++p) {
                unsigned int u = qrow[p];
                acc = fmaf(bf2f_lo(u), kf[2 * p],     acc);
                acc = fmaf(bf2f_hi(u), kf[2 * p + 1], acc);
            }
            float pij = __expf(0.25f * acc - ms[i]) * linv[i];
            const unsigned int* vrow = qkvg + (2 * LSEQ + i) * 9;
#pragma unroll
            for (int p = 0; p < 8; ++p) {
                unsigned int u = vrow[p];
                o[2 * p]     = fmaf(pij, bf2f_lo(u), o[2 * p]);
                o[2 * p + 1] = fmaf(pij, bf2f_hi(u), o[2 * p + 1]);
            }
        }
        const unsigned int* grow = qkvg + (3 * LSEQ + j) * 9;
#pragma unroll
        for (int p = 0; p < 8; ++p) {
            unsigned int u = grow[p];
            o[2 * p]     *= bf2f_lo(u);
            o[2 * p + 1] *= bf2f_hi(u);
        }
        float* op = attn_out + ((long)(b * LSEQ + j)) * 64 + h * HDIM;
#pragma unroll
        for (int q4 = 0; q4 < 4; ++q4) {
            ((float4*)op)[q4] = make_float4(o[4 * q4], o[4 * q4 + 1], o[4 * q4 + 2], o[4 * q4 + 3]);
        }
    }
}

// ---------- generic projection: out[t,c] = R[t,c] + bias[c] + sum_k act(A[t,k]) * W[c,k] ----------
// A contiguous [M][K]; token t -> (i0 = t/384, j0 = t%384) for strided R / out.
template <int K, typename AT, typename OT>
__global__ __launch_bounds__(256, 2) void proj_kernel(
    const AT* __restrict__ A,
    const float* __restrict__ W, const float* __restrict__ Bv,
    const float* R, long rs0, long rs1,
    OT* out, long os0, long os1,
    int act)
{
    const int tid  = threadIdx.x;
    const int wave = tid >> 6;
    const int lane = tid & 63;
    const int colBase = blockIdx.y * 64;

    __shared__ unsigned int wl[(K / 2) * 64];
    __shared__ float abuf[4][K];

    for (int e = tid; e < (K / 2) * 64; e += 256) {
        int kk = e >> 6, c = e & 63;
        const float* wp = W + (long)(colBase + c) * K + 2 * kk;
        wl[e] = (unsigned int)f2bf(wp[0]) | ((unsigned int)f2bf(wp[1]) << 16);
    }
    __syncthreads();

    const float bias = Bv[colBase + lane];
    const int t0 = (blockIdx.x * 4 + wave) * 24;

    for (int it = 0; it < 24; ++it) {
        int t = t0 + it;
#pragma unroll
        for (int k = lane; k < K; k += 64) {
            float a = ldval(&A[(long)t * K + k]);
            if (act) a = a / (1.f + __expf(-a));   // silu
            abuf[wave][k] = a;
        }
        __syncthreads();
        float acc = 0.f;
#pragma unroll
        for (int kk = 0; kk < K / 2; ++kk) {
            unsigned int u = wl[kk * 64 + lane];
            acc = fmaf(abuf[wave][2 * kk],     bf2f_lo(u), acc);
            acc = fmaf(abuf[wave][2 * kk + 1], bf2f_hi(u), acc);
        }
        int i0 = t / 384, j0 = t - i0 * 384;
        long co = colBase + lane;
        float val = acc + bias;
        if (R) val += R[(long)i0 * rs0 + (long)j0 * rs1 + co];
        stval(&out[(long)i0 * os0 + (long)j0 * os1 + co], val);
        __syncthreads();
    }
}

// ---------- launch ----------
extern "C" void kernel_launch(void* const* d_in, const int* in_sizes, int n_in,
                              void* d_out, int out_size, void* d_ws, size_t ws_size,
                              hipStream_t stream)
{
    const float* edge     = (const float*)d_in[0];
    const float* r_ln_g   = (const float*)d_in[1];
    const float* r_ln_b   = (const float*)d_in[2];
    const float* r_qkv_w  = (const float*)d_in[3];
    const float* r_gate_w = (const float*)d_in[4];
    const float* r_gate_b = (const float*)d_in[5];
    const float* r_fin_w  = (const float*)d_in[6];
    const float* r_fin_b  = (const float*)d_in[7];
    const float* c_ln_g   = (const float*)d_in[8];
    const float* c_ln_b   = (const float*)d_in[9];
    const float* c_qkv_w  = (const float*)d_in[10];
    const float* c_gate_w = (const float*)d_in[11];
    const float* c_gate_b = (const float*)d_in[12];
    const float* c_fin_w  = (const float*)d_in[13];
    const float* c_fin_b  = (const float*)d_in[14];
    const float* ff_w1    = (const float*)d_in[15];
    const float* ff_b1    = (const float*)d_in[16];
    const float* ff_w2    = (const float*)d_in[17];
    const float* ff_b2    = (const float*)d_in[18];

    char* ws = (char*)d_ws;
    float* attn = (float*)ws;                                   // 384*384*64 f32 = 37,748,736 B
    float* y    = (float*)(ws + 37748736);                      // 384*384*128 f32 = 75,497,472 B
    unsigned short* hbuf = (unsigned short*)(ws + 37748736 + 75497472); // 147456*256 bf16 = 75,497,472 B

    const long LD = 49152; // 384*128

    // row attention
    attn_kernel<<<dim3(LSEQ, NHEADS), 256, 0, stream>>>(
        edge, LD, 128, r_ln_g, r_ln_b, r_qkv_w, r_gate_w, r_gate_b, attn);
    proj_kernel<64, float, float><<<dim3(1536, 2), 256, 0, stream>>>(
        attn, r_fin_w, r_fin_b, edge, LD, 128, y, LD, 128, 0);

    // column attention (x viewed transposed via strides)
    attn_kernel<<<dim3(LSEQ, NHEADS), 256, 0, stream>>>(
        y, 128, LD, c_ln_g, c_ln_b, c_qkv_w, c_gate_w, c_gate_b, attn);
    // write back un-transposed, in place over y (same element per thread)
    proj_kernel<64, float, float><<<dim3(1536, 2), 256, 0, stream>>>(
        attn, c_fin_w, c_fin_b, y, 128, LD, y, 128, LD, 0);

    // feed-forward
    proj_kernel<128, float, unsigned short><<<dim3(1536, 4), 256, 0, stream>>>(
        y, ff_w1, ff_b1, nullptr, 0, 0, hbuf, 98304, 256, 1);
    proj_kernel<256, unsigned short, float><<<dim3(1536, 2), 256, 0, stream>>>(
        hbuf, ff_w2, ff_b2, y, LD, 128, (float*)d_out, LD, 128, 1);
}

// Round 3
// 1725.985 us; speedup vs baseline: 2.0380x; 2.0380x over previous
//
#include <hip/hip_runtime.h>

#define LSEQ 384
#define DIM 128
#define NHEADS 4
#define HDIM 16

typedef __attribute__((ext_vector_type(8))) short bf16x8;
typedef __attribute__((ext_vector_type(4))) float f32x4;

#define MFMA32(A,B,C) __builtin_amdgcn_mfma_f32_16x16x32_bf16(A,B,C,0,0,0)

// ---------- helpers ----------
__device__ __forceinline__ float bf2f_lo(unsigned int u) { return __uint_as_float(u << 16); }
__device__ __forceinline__ float bf2f_hi(unsigned int u) { return __uint_as_float(u & 0xFFFF0000u); }
__device__ __forceinline__ float bf2f_s(unsigned short s) { return __uint_as_float(((unsigned int)s) << 16); }
__device__ __forceinline__ unsigned short f2bf(float f) {
    unsigned int u = __float_as_uint(f);
    u += 0x7FFFu + ((u >> 16) & 1u);   // round-to-nearest-even
    return (unsigned short)(u >> 16);
}
__device__ __forceinline__ float wred_sum(float v) {
#pragma unroll
    for (int off = 32; off > 0; off >>= 1) v += __shfl_xor(v, off, 64);
    return v;
}
__device__ __forceinline__ float ldval(const float* p) { return *p; }
__device__ __forceinline__ float ldval(const unsigned short* p) { return __uint_as_float(((unsigned int)*p) << 16); }
__device__ __forceinline__ void stval(float* p, float v) { *p = v; }
__device__ __forceinline__ void stval(unsigned short* p, float v) { *p = f2bf(v); }

// ================= qkvg: LN + qkv/gate projection via MFMA =================
// Writes q*(0.25*log2e), k, v, sigmoid(gate) as bf16 into [b][h][n][16] layout.
#define XSTR 138   // LDS row stride in bf16
__global__ __launch_bounds__(256, 2) void qkvg_kernel(
    const float* __restrict__ x, long sb, long sn,
    const float* __restrict__ ln_g, const float* __restrict__ ln_b,
    const float* __restrict__ w_qkv, const float* __restrict__ w_gate,
    const float* __restrict__ b_gate,
    unsigned short* __restrict__ qws, unsigned short* __restrict__ kws,
    unsigned short* __restrict__ vws, unsigned short* __restrict__ gws)
{
    const int b   = blockIdx.x;
    const int q4  = blockIdx.y;          // token quarter (96 tokens each)
    const int tid = threadIdx.x, wave = tid >> 6, lane = tid & 63;
    const int jl  = lane & 15, g = lane >> 4;

    __shared__ __align__(16) unsigned short xn[96 * XSTR];
    __shared__ __align__(16) unsigned short xr[96 * XSTR];

    // ---- weight B-frags (16x16x32): wave owns n-tiles wave*4 .. wave*4+3
    bf16x8 wfrag[4][4];
    float gbias[4];
#pragma unroll
    for (int t = 0; t < 4; ++t) {
        int nt = wave * 4 + t;
        int c  = nt * 16 + jl;
        const float* wr;
        float scale;
        if (nt < 12) { wr = w_qkv + (long)c * DIM; scale = (nt < 4) ? 0.36067376022224085f : 1.0f; gbias[t] = 0.f; }
        else         { wr = w_gate + (long)(c - 192) * DIM; scale = 1.0f; gbias[t] = b_gate[c - 192]; }
#pragma unroll
        for (int ks = 0; ks < 4; ++ks) {
            int k0 = ks * 32 + g * 8;
            float4 w0 = *(const float4*)(wr + k0);
            float4 w1 = *(const float4*)(wr + k0 + 4);
            bf16x8 f;
            f[0] = (short)f2bf(w0.x * scale); f[1] = (short)f2bf(w0.y * scale);
            f[2] = (short)f2bf(w0.z * scale); f[3] = (short)f2bf(w0.w * scale);
            f[4] = (short)f2bf(w1.x * scale); f[5] = (short)f2bf(w1.y * scale);
            f[6] = (short)f2bf(w1.z * scale); f[7] = (short)f2bf(w1.w * scale);
            wfrag[t][ks] = f;
        }
    }

    // ---- LayerNorm: 24 tokens per wave, stage normed + raw bf16 into LDS
    const float* xbase = x + (long)b * sb + (long)(q4 * 96) * sn;
    const float lg0 = ln_g[lane], lg1 = ln_g[lane + 64];
    const float lb0 = ln_b[lane], lb1 = ln_b[lane + 64];
    for (int i = 0; i < 24; ++i) {
        int tk = wave * 24 + i;
        const float* xp = xbase + (long)tk * sn;
        float x0 = xp[lane], x1 = xp[lane + 64];
        float s  = wred_sum(x0 + x1);
        float sq = wred_sum(x0 * x0 + x1 * x1);
        float mean = s * (1.f / 128.f);
        float var  = sq * (1.f / 128.f) - mean * mean;
        float inv  = rsqrtf(var + 1e-5f);
        xn[tk * XSTR + lane]      = f2bf((x0 - mean) * inv * lg0 + lb0);
        xn[tk * XSTR + lane + 64] = f2bf((x1 - mean) * inv * lg1 + lb1);
        xr[tk * XSTR + lane]      = f2bf(x0);
        xr[tk * XSTR + lane + 64] = f2bf(x1);
    }
    __syncthreads();

    // ---- GEMM: 6 m-tiles x 4 n-tiles x 4 k-steps (16x16x32)
    const unsigned int* a32 = (const unsigned int*)((wave == 3) ? xr : xn);
    for (int mt = 0; mt < 6; ++mt) {
        bf16x8 af[4];
#pragma unroll
        for (int ks = 0; ks < 4; ++ks) {
            int adw = (mt * 16 + jl) * (XSTR / 2) + ks * 16 + g * 4;
            union { unsigned int u[4]; bf16x8 v; } cv;
            cv.u[0] = a32[adw]; cv.u[1] = a32[adw + 1];
            cv.u[2] = a32[adw + 2]; cv.u[3] = a32[adw + 3];
            af[ks] = cv.v;
        }
#pragma unroll
        for (int t = 0; t < 4; ++t) {
            int nt = wave * 4 + t;
            f32x4 acc = {0.f, 0.f, 0.f, 0.f};
#pragma unroll
            for (int ks = 0; ks < 4; ++ks) acc = MFMA32(af[ks], wfrag[t][ks], acc);
            int mat = nt >> 2, hh = nt & 3;
            unsigned short* outp = (mat == 0) ? qws : (mat == 1) ? kws : (mat == 2) ? vws : gws;
            long base = (((long)b * NHEADS + hh) * LSEQ + q4 * 96 + mt * 16 + g * 4) * HDIM + jl;
            if (mat == 3) {
#pragma unroll
                for (int r = 0; r < 4; ++r) {
                    float v = 1.f / (1.f + __expf(-(acc[r] + gbias[t])));
                    outp[base + r * HDIM] = f2bf(v);
                }
            } else {
#pragma unroll
                for (int r = 0; r < 4; ++r) outp[base + r * HDIM] = f2bf(acc[r]);
            }
        }
    }
}

// ================= attention core: S=QK^T, softmax over j, O=P^T V, gate ===
// q/k rows in LDS: stride 24 shorts (48B, 16B-aligned). frag: quads 0,1 hold
// d=0..15 (b128 load), quads 2,3 zero (K=32 zero-padded).
__global__ __launch_bounds__(256, 2) void attn_core_kernel(
    const unsigned short* __restrict__ qws, const unsigned short* __restrict__ kws,
    const unsigned short* __restrict__ vws, const unsigned short* __restrict__ gws,
    float* __restrict__ attn_out)
{
    const int b = blockIdx.x, h = blockIdx.y;
    const int tid = threadIdx.x, wave = tid >> 6, lane = tid & 63;
    const int jl  = lane & 15, g = lane >> 4;

    __shared__ __align__(16) unsigned short qs[LSEQ * 24];   // 18432 B
    __shared__ __align__(16) unsigned short ks[LSEQ * 24];   // 18432 B
    __shared__ __align__(16) unsigned short vs[LSEQ * 18];   // 13824 B
    __shared__ __align__(16) unsigned short gs[LSEQ * 16];   // 12288 B
    __shared__ float linv[LSEQ];                             //  1536 B  (total 64512)

    const long goff = ((long)b * NHEADS + h) * (LSEQ * HDIM);

    // ---- stage q,k (stride 24), v (stride 18), g (stride 16)
    {
        const uint4* gq = (const uint4*)(qws + goff);
        const uint4* gk = (const uint4*)(kws + goff);
        unsigned int* q32 = (unsigned int*)qs;
        unsigned int* k32 = (unsigned int*)ks;
        for (int e = tid; e < 768; e += 256) {
            int tk = e >> 1, hf = e & 1;
            *(uint4*)(q32 + tk * 12 + hf * 4) = gq[e];
            *(uint4*)(k32 + tk * 12 + hf * 4) = gk[e];
        }
        const unsigned int* gv = (const unsigned int*)(vws + goff);
        unsigned int* v32 = (unsigned int*)vs;
        for (int e = tid; e < 3072; e += 256) {
            int tk = e >> 3, j = e & 7;
            v32[tk * 9 + j] = gv[e];
        }
        const uint4* gg = (const uint4*)(gws + goff);
        uint4* g128 = (uint4*)gs;
        for (int e = tid; e < 768; e += 256) g128[e] = gg[e];
    }
    __syncthreads();

    const unsigned int* q32 = (const unsigned int*)qs;
    const unsigned int* k32 = (const unsigned int*)ks;

    // own-tile frags (tile = wave*6 + t)
    bf16x8 Q8o[6], K8o[6];
#pragma unroll
    for (int t = 0; t < 6; ++t) {
        union { unsigned int u[4]; bf16x8 v; } cq, ck;
        if (g < 2) {
            int adw = ((wave * 6 + t) * 16 + jl) * 12 + g * 4;
            uint4 xq = *(const uint4*)(q32 + adw);
            uint4 xk = *(const uint4*)(k32 + adw);
            cq.u[0] = xq.x; cq.u[1] = xq.y; cq.u[2] = xq.z; cq.u[3] = xq.w;
            ck.u[0] = xk.x; ck.u[1] = xk.y; ck.u[2] = xk.z; ck.u[3] = xk.w;
        } else {
            cq.u[0] = cq.u[1] = cq.u[2] = cq.u[3] = 0;
            ck.u[0] = ck.u[1] = ck.u[2] = ck.u[3] = 0;
        }
        Q8o[t] = cq.v; K8o[t] = ck.v;
    }

    const short oneb = (short)0x3F80;
    bf16x8 ones8 = { oneb, oneb, oneb, oneb, oneb, oneb, oneb, oneb };
    const f32x4 fz = {0.f, 0.f, 0.f, 0.f};

    // ---- pass 1: l_i = sum_j 2^(s'_ij); scores pre-scaled via q by 0.25*log2e
    for (int t = 0; t < 6; ++t) {
        f32x4 lacc = fz;
        for (int u = 0; u < 12; ++u) {
            union { unsigned int w[4]; bf16x8 v; } c0, c1;
            if (g < 2) {
                int a0 = ((2 * u) * 16 + jl) * 12 + g * 4;
                uint4 x0 = *(const uint4*)(k32 + a0);
                uint4 x1 = *(const uint4*)(k32 + a0 + 192);   // next tile (+16 rows)
                c0.w[0] = x0.x; c0.w[1] = x0.y; c0.w[2] = x0.z; c0.w[3] = x0.w;
                c1.w[0] = x1.x; c1.w[1] = x1.y; c1.w[2] = x1.z; c1.w[3] = x1.w;
            } else {
                c0.w[0] = c0.w[1] = c0.w[2] = c0.w[3] = 0;
                c1.w[0] = c1.w[1] = c1.w[2] = c1.w[3] = 0;
            }
            f32x4 s0 = MFMA32(c0.v, Q8o[t], fz);
            f32x4 s1 = MFMA32(c1.v, Q8o[t], fz);
            bf16x8 ef;
            ef[0] = (short)f2bf(exp2f(s0[0])); ef[1] = (short)f2bf(exp2f(s0[1]));
            ef[2] = (short)f2bf(exp2f(s0[2])); ef[3] = (short)f2bf(exp2f(s0[3]));
            ef[4] = (short)f2bf(exp2f(s1[0])); ef[5] = (short)f2bf(exp2f(s1[1]));
            ef[6] = (short)f2bf(exp2f(s1[2])); ef[7] = (short)f2bf(exp2f(s1[3]));
            lacc = MFMA32(ef, ones8, lacc);
        }
        if (jl == 0) {
#pragma unroll
            for (int r = 0; r < 4; ++r) linv[(wave * 6 + t) * 16 + g * 4 + r] = 1.f / lacc[r];
        }
    }
    __syncthreads();

    // ---- V-hat B-frags with the tau permutation: slot (g,jj) -> token
    //      tau = 32u + (jj<4 ? g*4+jj : 16 + g*4 + jj-4)
    bf16x8 VB8[12];
#pragma unroll
    for (int u = 0; u < 12; ++u) {
        bf16x8 vv;
#pragma unroll
        for (int jj = 0; jj < 8; ++jj) {
            int token = 32 * u + ((jj < 4) ? (g * 4 + jj) : (16 + g * 4 + jj - 4));
            vv[jj] = (short)f2bf(bf2f_s(vs[token * 18 + jl]) * linv[token]);
        }
        VB8[u] = vv;
    }

    // ---- pass 2: O[j][d] = sum_i 2^(s'_ij) * vhat[i][d]; gate & store
    for (int t = 0; t < 6; ++t) {
        f32x4 o = fz;
        for (int u = 0; u < 12; ++u) {
            union { unsigned int w[4]; bf16x8 v; } c0, c1;
            if (g < 2) {
                int a0 = ((2 * u) * 16 + jl) * 12 + g * 4;
                uint4 x0 = *(const uint4*)(q32 + a0);
                uint4 x1 = *(const uint4*)(q32 + a0 + 192);
                c0.w[0] = x0.x; c0.w[1] = x0.y; c0.w[2] = x0.z; c0.w[3] = x0.w;
                c1.w[0] = x1.x; c1.w[1] = x1.y; c1.w[2] = x1.z; c1.w[3] = x1.w;
            } else {
                c0.w[0] = c0.w[1] = c0.w[2] = c0.w[3] = 0;
                c1.w[0] = c1.w[1] = c1.w[2] = c1.w[3] = 0;
            }
            f32x4 s0 = MFMA32(c0.v, K8o[t], fz);   // D[i_local (tile 2u)][j_local]
            f32x4 s1 = MFMA32(c1.v, K8o[t], fz);   // D[i_local (tile 2u+1)][j_local]
            bf16x8 pf;
            pf[0] = (short)f2bf(exp2f(s0[0])); pf[1] = (short)f2bf(exp2f(s0[1]));
            pf[2] = (short)f2bf(exp2f(s0[2])); pf[3] = (short)f2bf(exp2f(s0[3]));
            pf[4] = (short)f2bf(exp2f(s1[0])); pf[5] = (short)f2bf(exp2f(s1[1]));
            pf[6] = (short)f2bf(exp2f(s1[2])); pf[7] = (short)f2bf(exp2f(s1[3]));
            o = MFMA32(pf, VB8[u], o);             // A: m=j,k=tau(i); B: k=tau(i),n=d
        }
#pragma unroll
        for (int r = 0; r < 4; ++r) {
            int jrow = (wave * 6 + t) * 16 + g * 4 + r;
            float gate = bf2f_s(gs[jrow * 16 + jl]);
            attn_out[((long)b * LSEQ + jrow) * 64 + h * HDIM + jl] = o[r] * gate;
        }
    }
}

// ---------- generic projection: out[t,c] = R[t,c] + bias[c] + sum_k act(A[t,k]) * W[c,k] ----------
template <int K, typename AT, typename OT>
__global__ __launch_bounds__(256, 2) void proj_kernel(
    const AT* __restrict__ A,
    const float* __restrict__ W, const float* __restrict__ Bv,
    const float* R, long rs0, long rs1,
    OT* out, long os0, long os1,
    int act)
{
    const int tid  = threadIdx.x;
    const int wave = tid >> 6;
    const int lane = tid & 63;
    const int colBase = blockIdx.y * 64;

    __shared__ unsigned int wl[(K / 2) * 64];
    __shared__ float abuf[4][K];

    for (int e = tid; e < (K / 2) * 64; e += 256) {
        int kk = e >> 6, c = e & 63;
        const float* wp = W + (long)(colBase + c) * K + 2 * kk;
        wl[e] = (unsigned int)f2bf(wp[0]) | ((unsigned int)f2bf(wp[1]) << 16);
    }
    __syncthreads();

    const float bias = Bv[colBase + lane];
    const int t0 = (blockIdx.x * 4 + wave) * 24;

    for (int it = 0; it < 24; ++it) {
        int t = t0 + it;
#pragma unroll
        for (int k = lane; k < K; k += 64) {
            float a = ldval(&A[(long)t * K + k]);
            if (act) a = a / (1.f + __expf(-a));   // silu
            abuf[wave][k] = a;
        }
        __syncthreads();
        float acc = 0.f;
#pragma unroll
        for (int kk = 0; kk < K / 2; ++kk) {
            unsigned int u = wl[kk * 64 + lane];
            acc = fmaf(abuf[wave][2 * kk],     bf2f_lo(u), acc);
            acc = fmaf(abuf[wave][2 * kk + 1], bf2f_hi(u), acc);
        }
        int i0 = t / 384, j0 = t - i0 * 384;
        long co = colBase + lane;
        float val = acc + bias;
        if (R) val += R[(long)i0 * rs0 + (long)j0 * rs1 + co];
        stval(&out[(long)i0 * os0 + (long)j0 * os1 + co], val);
        __syncthreads();
    }
}

// ---------- launch ----------
extern "C" void kernel_launch(void* const* d_in, const int* in_sizes, int n_in,
                              void* d_out, int out_size, void* d_ws, size_t ws_size,
                              hipStream_t stream)
{
    const float* edge     = (const float*)d_in[0];
    const float* r_ln_g   = (const float*)d_in[1];
    const float* r_ln_b   = (const float*)d_in[2];
    const float* r_qkv_w  = (const float*)d_in[3];
    const float* r_gate_w = (const float*)d_in[4];
    const float* r_gate_b = (const float*)d_in[5];
    const float* r_fin_w  = (const float*)d_in[6];
    const float* r_fin_b  = (const float*)d_in[7];
    const float* c_ln_g   = (const float*)d_in[8];
    const float* c_ln_b   = (const float*)d_in[9];
    const float* c_qkv_w  = (const float*)d_in[10];
    const float* c_gate_w = (const float*)d_in[11];
    const float* c_gate_b = (const float*)d_in[12];
    const float* c_fin_w  = (const float*)d_in[13];
    const float* c_fin_b  = (const float*)d_in[14];
    const float* ff_w1    = (const float*)d_in[15];
    const float* ff_b1    = (const float*)d_in[16];
    const float* ff_w2    = (const float*)d_in[17];
    const float* ff_b2    = (const float*)d_in[18];

    char* ws = (char*)d_ws;
    // region A (75,497,472 B): qkvg buffers during attention; hbuf during FF
    unsigned short* qb = (unsigned short*)ws;
    unsigned short* kb = qb + 9437184;
    unsigned short* vb = qb + 2 * 9437184;
    unsigned short* gb = qb + 3 * 9437184;
    unsigned short* hbuf = (unsigned short*)ws;                 // reuse A in FF phase
    float* attn = (float*)(ws + 75497472);                      // 37,748,736 B
    float* y    = (float*)(ws + 75497472 + 37748736);           // 75,497,472 B

    const long LD = 49152; // 384*128

    // ---- row attention
    qkvg_kernel<<<dim3(LSEQ, 4), 256, 0, stream>>>(
        edge, LD, 128, r_ln_g, r_ln_b, r_qkv_w, r_gate_w, r_gate_b, qb, kb, vb, gb);
    attn_core_kernel<<<dim3(LSEQ, NHEADS), 256, 0, stream>>>(qb, kb, vb, gb, attn);
    proj_kernel<64, float, float><<<dim3(1536, 2), 256, 0, stream>>>(
        attn, r_fin_w, r_fin_b, edge, LD, 128, y, LD, 128, 0);

    // ---- column attention (x viewed transposed via strides)
    qkvg_kernel<<<dim3(LSEQ, 4), 256, 0, stream>>>(
        y, 128, LD, c_ln_g, c_ln_b, c_qkv_w, c_gate_w, c_gate_b, qb, kb, vb, gb);
    attn_core_kernel<<<dim3(LSEQ, NHEADS), 256, 0, stream>>>(qb, kb, vb, gb, attn);
    proj_kernel<64, float, float><<<dim3(1536, 2), 256, 0, stream>>>(
        attn, c_fin_w, c_fin_b, y, 128, LD, y, 128, LD, 0);

    // ---- feed-forward
    proj_kernel<128, float, unsigned short><<<dim3(1536, 4), 256, 0, stream>>>(
        y, ff_w1, ff_b1, nullptr, 0, 0, hbuf, 98304, 256, 1);
    proj_kernel<256, unsigned short, float><<<dim3(1536, 2), 256, 0, stream>>>(
        hbuf, ff_w2, ff_b2, y, LD, 128, (float*)d_out, LD, 128, 1);
}

// Round 4
// 1119.109 us; speedup vs baseline: 3.1433x; 1.5423x over previous
//
#include <hip/hip_runtime.h>

#define LSEQ 384
#define DIM 128
#define NHEADS 4
#define HDIM 16

typedef __attribute__((ext_vector_type(8))) short bf16x8;
typedef __attribute__((ext_vector_type(4))) float f32x4;

#define MFMA32(A,B,C) __builtin_amdgcn_mfma_f32_16x16x32_bf16(A,B,C,0,0,0)

// ---------- helpers ----------
__device__ __forceinline__ float bf2f_lo(unsigned int u) { return __uint_as_float(u << 16); }
__device__ __forceinline__ float bf2f_hi(unsigned int u) { return __uint_as_float(u & 0xFFFF0000u); }
__device__ __forceinline__ float bf2f_s(unsigned short s) { return __uint_as_float(((unsigned int)s) << 16); }
__device__ __forceinline__ unsigned short f2bf(float f) {
    unsigned int u = __float_as_uint(f);
    u += 0x7FFFu + ((u >> 16) & 1u);   // round-to-nearest-even
    return (unsigned short)(u >> 16);
}
__device__ __forceinline__ float wred_sum(float v) {
#pragma unroll
    for (int off = 32; off > 0; off >>= 1) v += __shfl_xor(v, off, 64);
    return v;
}
__device__ __forceinline__ void stval(float* p, float v) { *p = v; }
__device__ __forceinline__ void stval(unsigned short* p, float v) { *p = f2bf(v); }
__device__ __forceinline__ float2 ldpair(const float* A, long e2) {
    return *(const float2*)(A + 2 * e2);
}
__device__ __forceinline__ float2 ldpair(const unsigned short* A, long e2) {
    unsigned int u = *(const unsigned int*)(A + 2 * e2);
    return make_float2(bf2f_lo(u), bf2f_hi(u));
}

// ================= qkvg: LN + qkv/gate projection via MFMA =================
// Writes q*(0.25*log2e), k, v, sigmoid(gate) as bf16 into [b][h][n][16] layout.
#define XSTR 138   // LDS row stride in bf16
__global__ __launch_bounds__(256, 2) void qkvg_kernel(
    const float* __restrict__ x, long sb, long sn,
    const float* __restrict__ ln_g, const float* __restrict__ ln_b,
    const float* __restrict__ w_qkv, const float* __restrict__ w_gate,
    const float* __restrict__ b_gate,
    unsigned short* __restrict__ qws, unsigned short* __restrict__ kws,
    unsigned short* __restrict__ vws, unsigned short* __restrict__ gws)
{
    const int b   = blockIdx.x;
    const int q4  = blockIdx.y;          // token quarter (96 tokens each)
    const int tid = threadIdx.x, wave = tid >> 6, lane = tid & 63;
    const int jl  = lane & 15, g = lane >> 4;

    __shared__ __align__(16) unsigned short xn[96 * XSTR];
    __shared__ __align__(16) unsigned short xr[96 * XSTR];

    // ---- weight B-frags (16x16x32): wave owns n-tiles wave*4 .. wave*4+3
    bf16x8 wfrag[4][4];
    float gbias[4];
#pragma unroll
    for (int t = 0; t < 4; ++t) {
        int nt = wave * 4 + t;
        int c  = nt * 16 + jl;
        const float* wr;
        float scale;
        if (nt < 12) { wr = w_qkv + (long)c * DIM; scale = (nt < 4) ? 0.36067376022224085f : 1.0f; gbias[t] = 0.f; }
        else         { wr = w_gate + (long)(c - 192) * DIM; scale = 1.0f; gbias[t] = b_gate[c - 192]; }
#pragma unroll
        for (int ks = 0; ks < 4; ++ks) {
            int k0 = ks * 32 + g * 8;
            float4 w0 = *(const float4*)(wr + k0);
            float4 w1 = *(const float4*)(wr + k0 + 4);
            bf16x8 f;
            f[0] = (short)f2bf(w0.x * scale); f[1] = (short)f2bf(w0.y * scale);
            f[2] = (short)f2bf(w0.z * scale); f[3] = (short)f2bf(w0.w * scale);
            f[4] = (short)f2bf(w1.x * scale); f[5] = (short)f2bf(w1.y * scale);
            f[6] = (short)f2bf(w1.z * scale); f[7] = (short)f2bf(w1.w * scale);
            wfrag[t][ks] = f;
        }
    }

    // ---- LayerNorm: 24 tokens per wave, stage normed + raw bf16 into LDS
    const float* xbase = x + (long)b * sb + (long)(q4 * 96) * sn;
    const float lg0 = ln_g[lane], lg1 = ln_g[lane + 64];
    const float lb0 = ln_b[lane], lb1 = ln_b[lane + 64];
    for (int i = 0; i < 24; ++i) {
        int tk = wave * 24 + i;
        const float* xp = xbase + (long)tk * sn;
        float x0 = xp[lane], x1 = xp[lane + 64];
        float s  = wred_sum(x0 + x1);
        float sq = wred_sum(x0 * x0 + x1 * x1);
        float mean = s * (1.f / 128.f);
        float var  = sq * (1.f / 128.f) - mean * mean;
        float inv  = rsqrtf(var + 1e-5f);
        xn[tk * XSTR + lane]      = f2bf((x0 - mean) * inv * lg0 + lb0);
        xn[tk * XSTR + lane + 64] = f2bf((x1 - mean) * inv * lg1 + lb1);
        xr[tk * XSTR + lane]      = f2bf(x0);
        xr[tk * XSTR + lane + 64] = f2bf(x1);
    }
    __syncthreads();

    // ---- GEMM: 6 m-tiles x 4 n-tiles x 4 k-steps (16x16x32)
    const unsigned int* a32 = (const unsigned int*)((wave == 3) ? xr : xn);
    for (int mt = 0; mt < 6; ++mt) {
        bf16x8 af[4];
#pragma unroll
        for (int ks = 0; ks < 4; ++ks) {
            int adw = (mt * 16 + jl) * (XSTR / 2) + ks * 16 + g * 4;
            union { unsigned int u[4]; bf16x8 v; } cv;
            cv.u[0] = a32[adw]; cv.u[1] = a32[adw + 1];
            cv.u[2] = a32[adw + 2]; cv.u[3] = a32[adw + 3];
            af[ks] = cv.v;
        }
#pragma unroll
        for (int t = 0; t < 4; ++t) {
            int nt = wave * 4 + t;
            f32x4 acc = {0.f, 0.f, 0.f, 0.f};
#pragma unroll
            for (int ks = 0; ks < 4; ++ks) acc = MFMA32(af[ks], wfrag[t][ks], acc);
            int mat = nt >> 2, hh = nt & 3;
            unsigned short* outp = (mat == 0) ? qws : (mat == 1) ? kws : (mat == 2) ? vws : gws;
            long base = (((long)b * NHEADS + hh) * LSEQ + q4 * 96 + mt * 16 + g * 4) * HDIM + jl;
            if (mat == 3) {
#pragma unroll
                for (int r = 0; r < 4; ++r) {
                    float v = 1.f / (1.f + __expf(-(acc[r] + gbias[t])));
                    outp[base + r * HDIM] = f2bf(v);
                }
            } else {
#pragma unroll
                for (int r = 0; r < 4; ++r) outp[base + r * HDIM] = f2bf(acc[r]);
            }
        }
    }
}

// ================= attention core: S=QK^T, softmax over j, O=P^T V, gate ===
__global__ __launch_bounds__(256, 2) void attn_core_kernel(
    const unsigned short* __restrict__ qws, const unsigned short* __restrict__ kws,
    const unsigned short* __restrict__ vws, const unsigned short* __restrict__ gws,
    float* __restrict__ attn_out)
{
    const int b = blockIdx.x, h = blockIdx.y;
    const int tid = threadIdx.x, wave = tid >> 6, lane = tid & 63;
    const int jl  = lane & 15, g = lane >> 4;

    __shared__ __align__(16) unsigned short qs[LSEQ * 24];   // 18432 B
    __shared__ __align__(16) unsigned short ks[LSEQ * 24];   // 18432 B
    __shared__ __align__(16) unsigned short vs[LSEQ * 18];   // 13824 B
    __shared__ __align__(16) unsigned short gs[LSEQ * 16];   // 12288 B
    __shared__ float linv[LSEQ];                             //  1536 B  (total 64512)

    const long goff = ((long)b * NHEADS + h) * (LSEQ * HDIM);

    // ---- stage q,k (stride 24), v (stride 18), g (stride 16)
    {
        const uint4* gq = (const uint4*)(qws + goff);
        const uint4* gk = (const uint4*)(kws + goff);
        unsigned int* q32s = (unsigned int*)qs;
        unsigned int* k32s = (unsigned int*)ks;
        for (int e = tid; e < 768; e += 256) {
            int tk = e >> 1, hf = e & 1;
            *(uint4*)(q32s + tk * 12 + hf * 4) = gq[e];
            *(uint4*)(k32s + tk * 12 + hf * 4) = gk[e];
        }
        const unsigned int* gv = (const unsigned int*)(vws + goff);
        unsigned int* v32 = (unsigned int*)vs;
        for (int e = tid; e < 3072; e += 256) {
            int tk = e >> 3, j = e & 7;
            v32[tk * 9 + j] = gv[e];
        }
        const uint4* gg = (const uint4*)(gws + goff);
        uint4* g128 = (uint4*)gs;
        for (int e = tid; e < 768; e += 256) g128[e] = gg[e];
    }
    __syncthreads();

    const unsigned int* q32 = (const unsigned int*)qs;
    const unsigned int* k32 = (const unsigned int*)ks;

    // own-tile frags (tile = wave*6 + t)
    bf16x8 Q8o[6], K8o[6];
#pragma unroll
    for (int t = 0; t < 6; ++t) {
        union { unsigned int u[4]; bf16x8 v; } cq, ck;
        if (g < 2) {
            int adw = ((wave * 6 + t) * 16 + jl) * 12 + g * 4;
            uint4 xq = *(const uint4*)(q32 + adw);
            uint4 xk = *(const uint4*)(k32 + adw);
            cq.u[0] = xq.x; cq.u[1] = xq.y; cq.u[2] = xq.z; cq.u[3] = xq.w;
            ck.u[0] = xk.x; ck.u[1] = xk.y; ck.u[2] = xk.z; ck.u[3] = xk.w;
        } else {
            cq.u[0] = cq.u[1] = cq.u[2] = cq.u[3] = 0;
            ck.u[0] = ck.u[1] = ck.u[2] = ck.u[3] = 0;
        }
        Q8o[t] = cq.v; K8o[t] = ck.v;
    }

    const short oneb = (short)0x3F80;
    bf16x8 ones8 = { oneb, oneb, oneb, oneb, oneb, oneb, oneb, oneb };
    const f32x4 fz = {0.f, 0.f, 0.f, 0.f};

    // ---- pass 1: l_i = sum_j 2^(s'_ij); scores pre-scaled via q by 0.25*log2e
    for (int t = 0; t < 6; ++t) {
        f32x4 lacc = fz;
        for (int u = 0; u < 12; ++u) {
            union { unsigned int w[4]; bf16x8 v; } c0, c1;
            if (g < 2) {
                int a0 = ((2 * u) * 16 + jl) * 12 + g * 4;
                uint4 x0 = *(const uint4*)(k32 + a0);
                uint4 x1 = *(const uint4*)(k32 + a0 + 192);   // next tile (+16 rows)
                c0.w[0] = x0.x; c0.w[1] = x0.y; c0.w[2] = x0.z; c0.w[3] = x0.w;
                c1.w[0] = x1.x; c1.w[1] = x1.y; c1.w[2] = x1.z; c1.w[3] = x1.w;
            } else {
                c0.w[0] = c0.w[1] = c0.w[2] = c0.w[3] = 0;
                c1.w[0] = c1.w[1] = c1.w[2] = c1.w[3] = 0;
            }
            f32x4 s0 = MFMA32(c0.v, Q8o[t], fz);
            f32x4 s1 = MFMA32(c1.v, Q8o[t], fz);
            bf16x8 ef;
            ef[0] = (short)f2bf(exp2f(s0[0])); ef[1] = (short)f2bf(exp2f(s0[1]));
            ef[2] = (short)f2bf(exp2f(s0[2])); ef[3] = (short)f2bf(exp2f(s0[3]));
            ef[4] = (short)f2bf(exp2f(s1[0])); ef[5] = (short)f2bf(exp2f(s1[1]));
            ef[6] = (short)f2bf(exp2f(s1[2])); ef[7] = (short)f2bf(exp2f(s1[3]));
            lacc = MFMA32(ef, ones8, lacc);
        }
        if (jl == 0) {
#pragma unroll
            for (int r = 0; r < 4; ++r) linv[(wave * 6 + t) * 16 + g * 4 + r] = 1.f / lacc[r];
        }
    }
    __syncthreads();

    // ---- V-hat B-frags with the tau permutation: slot (g,jj) -> token
    bf16x8 VB8[12];
#pragma unroll
    for (int u = 0; u < 12; ++u) {
        bf16x8 vv;
#pragma unroll
        for (int jj = 0; jj < 8; ++jj) {
            int token = 32 * u + ((jj < 4) ? (g * 4 + jj) : (16 + g * 4 + jj - 4));
            vv[jj] = (short)f2bf(bf2f_s(vs[token * 18 + jl]) * linv[token]);
        }
        VB8[u] = vv;
    }

    // ---- pass 2: O[j][d] = sum_i 2^(s'_ij) * vhat[i][d]; gate & store
    for (int t = 0; t < 6; ++t) {
        f32x4 o = fz;
        for (int u = 0; u < 12; ++u) {
            union { unsigned int w[4]; bf16x8 v; } c0, c1;
            if (g < 2) {
                int a0 = ((2 * u) * 16 + jl) * 12 + g * 4;
                uint4 x0 = *(const uint4*)(q32 + a0);
                uint4 x1 = *(const uint4*)(q32 + a0 + 192);
                c0.w[0] = x0.x; c0.w[1] = x0.y; c0.w[2] = x0.z; c0.w[3] = x0.w;
                c1.w[0] = x1.x; c1.w[1] = x1.y; c1.w[2] = x1.z; c1.w[3] = x1.w;
            } else {
                c0.w[0] = c0.w[1] = c0.w[2] = c0.w[3] = 0;
                c1.w[0] = c1.w[1] = c1.w[2] = c1.w[3] = 0;
            }
            f32x4 s0 = MFMA32(c0.v, K8o[t], fz);
            f32x4 s1 = MFMA32(c1.v, K8o[t], fz);
            bf16x8 pf;
            pf[0] = (short)f2bf(exp2f(s0[0])); pf[1] = (short)f2bf(exp2f(s0[1]));
            pf[2] = (short)f2bf(exp2f(s0[2])); pf[3] = (short)f2bf(exp2f(s0[3]));
            pf[4] = (short)f2bf(exp2f(s1[0])); pf[5] = (short)f2bf(exp2f(s1[1]));
            pf[6] = (short)f2bf(exp2f(s1[2])); pf[7] = (short)f2bf(exp2f(s1[3]));
            o = MFMA32(pf, VB8[u], o);
        }
#pragma unroll
        for (int r = 0; r < 4; ++r) {
            int jrow = (wave * 6 + t) * 16 + g * 4 + r;
            float gate = bf2f_s(gs[jrow * 16 + jl]);
            attn_out[((long)b * LSEQ + jrow) * 64 + h * HDIM + jl] = o[r] * gate;
        }
    }
}

// ========== MFMA projection: out[t,c] = R[t,c] + bias[c] + sum_k act(A[t,k])*W[c,k] ==========
// Block: 96 tokens x N cols (N = NT*64). Wave owns n-tiles wave*NT..wave*NT+NT-1.
// token t -> (i0 = t/384, j0 = t%384); 96 | 384 so i0 is block-constant.
template <int K, int NT, typename AT, typename OT, int ACT>
__global__ __launch_bounds__(256, 2) void mproj_kernel(
    const AT* __restrict__ A,
    const float* __restrict__ W, const float* __restrict__ Bv,
    const float* R, long rs0, long rs1,
    OT* out, long os0, long os1)
{
    constexpr int KS = K / 32;        // MFMA k-steps
    constexpr int RS = K / 2 + 4;     // LDS row stride in dwords (== 4 mod 32: 2-way max)
    const int tid = threadIdx.x, wave = tid >> 6, lane = tid & 63;
    const int jl = lane & 15, g = lane >> 4;

    __shared__ __align__(16) unsigned int abuf[96 * RS];

    // ---- weight B-frags + bias (per-lane col = nt*16+jl)
    bf16x8 wfrag[NT][KS];
    float bias[NT];
#pragma unroll
    for (int t = 0; t < NT; ++t) {
        int c = (wave * NT + t) * 16 + jl;
        const float* wr = W + (long)c * K;
        bias[t] = Bv[c];
#pragma unroll
        for (int ks = 0; ks < KS; ++ks) {
            int k0 = ks * 32 + g * 8;
            float4 w0 = *(const float4*)(wr + k0);
            float4 w1 = *(const float4*)(wr + k0 + 4);
            bf16x8 f;
            f[0] = (short)f2bf(w0.x); f[1] = (short)f2bf(w0.y);
            f[2] = (short)f2bf(w0.z); f[3] = (short)f2bf(w0.w);
            f[4] = (short)f2bf(w1.x); f[5] = (short)f2bf(w1.y);
            f[6] = (short)f2bf(w1.z); f[7] = (short)f2bf(w1.w);
            wfrag[t][ks] = f;
        }
    }

    // ---- stage act(A) as bf16 into LDS
    const long t0 = (long)blockIdx.x * 96;
    for (int e = tid; e < 96 * (K / 2); e += 256) {
        int row = e / (K / 2), cp = e % (K / 2);
        float2 a = ldpair(A, t0 * (K / 2) + e);
        if (ACT) {
            a.x = a.x / (1.f + __expf(-a.x));
            a.y = a.y / (1.f + __expf(-a.y));
        }
        abuf[row * RS + cp] = (unsigned int)f2bf(a.x) | ((unsigned int)f2bf(a.y) << 16);
    }
    __syncthreads();

    const int i0 = blockIdx.x >> 2;
    const int j0b = (blockIdx.x & 3) * 96;

    for (int mt = 0; mt < 6; ++mt) {
        bf16x8 af[KS];
#pragma unroll
        for (int ks = 0; ks < KS; ++ks) {
            int adw = (mt * 16 + jl) * RS + ks * 16 + g * 4;
            uint4 x = *(const uint4*)(abuf + adw);
            union { unsigned int u[4]; bf16x8 v; } cv;
            cv.u[0] = x.x; cv.u[1] = x.y; cv.u[2] = x.z; cv.u[3] = x.w;
            af[ks] = cv.v;
        }
#pragma unroll
        for (int t = 0; t < NT; ++t) {
            f32x4 acc = {0.f, 0.f, 0.f, 0.f};
#pragma unroll
            for (int ks = 0; ks < KS; ++ks) acc = MFMA32(af[ks], wfrag[t][ks], acc);
            const long co = (wave * NT + t) * 16 + jl;
#pragma unroll
            for (int r = 0; r < 4; ++r) {
                int j0 = j0b + mt * 16 + g * 4 + r;
                float val = acc[r] + bias[t];
                if (R) val += R[(long)i0 * rs0 + (long)j0 * rs1 + co];
                stval(&out[(long)i0 * os0 + (long)j0 * os1 + co], val);
            }
        }
    }
}

// ---------- launch ----------
extern "C" void kernel_launch(void* const* d_in, const int* in_sizes, int n_in,
                              void* d_out, int out_size, void* d_ws, size_t ws_size,
                              hipStream_t stream)
{
    const float* edge     = (const float*)d_in[0];
    const float* r_ln_g   = (const float*)d_in[1];
    const float* r_ln_b   = (const float*)d_in[2];
    const float* r_qkv_w  = (const float*)d_in[3];
    const float* r_gate_w = (const float*)d_in[4];
    const float* r_gate_b = (const float*)d_in[5];
    const float* r_fin_w  = (const float*)d_in[6];
    const float* r_fin_b  = (const float*)d_in[7];
    const float* c_ln_g   = (const float*)d_in[8];
    const float* c_ln_b   = (const float*)d_in[9];
    const float* c_qkv_w  = (const float*)d_in[10];
    const float* c_gate_w = (const float*)d_in[11];
    const float* c_gate_b = (const float*)d_in[12];
    const float* c_fin_w  = (const float*)d_in[13];
    const float* c_fin_b  = (const float*)d_in[14];
    const float* ff_w1    = (const float*)d_in[15];
    const float* ff_b1    = (const float*)d_in[16];
    const float* ff_w2    = (const float*)d_in[17];
    const float* ff_b2    = (const float*)d_in[18];

    char* ws = (char*)d_ws;
    // region A (75,497,472 B): qkvg buffers during attention; hbuf during FF
    unsigned short* qb = (unsigned short*)ws;
    unsigned short* kb = qb + 9437184;
    unsigned short* vb = qb + 2 * 9437184;
    unsigned short* gb = qb + 3 * 9437184;
    unsigned short* hbuf = (unsigned short*)ws;                 // reuse A in FF phase
    float* attn = (float*)(ws + 75497472);                      // 37,748,736 B
    float* y    = (float*)(ws + 75497472 + 37748736);           // 75,497,472 B

    const long LD = 49152; // 384*128

    // ---- row attention
    qkvg_kernel<<<dim3(LSEQ, 4), 256, 0, stream>>>(
        edge, LD, 128, r_ln_g, r_ln_b, r_qkv_w, r_gate_w, r_gate_b, qb, kb, vb, gb);
    attn_core_kernel<<<dim3(LSEQ, NHEADS), 256, 0, stream>>>(qb, kb, vb, gb, attn);
    mproj_kernel<64, 2, float, float, 0><<<1536, 256, 0, stream>>>(
        attn, r_fin_w, r_fin_b, edge, LD, 128, y, LD, 128);

    // ---- column attention (x viewed transposed via strides)
    qkvg_kernel<<<dim3(LSEQ, 4), 256, 0, stream>>>(
        y, 128, LD, c_ln_g, c_ln_b, c_qkv_w, c_gate_w, c_gate_b, qb, kb, vb, gb);
    attn_core_kernel<<<dim3(LSEQ, NHEADS), 256, 0, stream>>>(qb, kb, vb, gb, attn);
    mproj_kernel<64, 2, float, float, 0><<<1536, 256, 0, stream>>>(
        attn, c_fin_w, c_fin_b, y, 128, LD, y, 128, LD);

    // ---- feed-forward
    mproj_kernel<128, 4, float, unsigned short, 1><<<1536, 256, 0, stream>>>(
        y, ff_w1, ff_b1, nullptr, 0, 0, hbuf, 98304, 256);
    mproj_kernel<256, 2, unsigned short, float, 1><<<1536, 256, 0, stream>>>(
        hbuf, ff_w2, ff_b2, y, LD, 128, (float*)d_out, LD, 128);
}